// Round 2
// baseline (320.004 us; speedup 1.0000x reference)
//
#include <hip/hip_runtime.h>

#define N_FEAT 128          // feature count for both aggregation passes
#define HID 256
#define OUT_CH 128

// ---------------- CSR build ----------------

__global__ void zero_counts_kernel(int* __restrict__ counts, int n) {
    int i = blockIdx.x * blockDim.x + threadIdx.x;
    if (i < n) counts[i] = 0;
}

__global__ void count_kernel(const int* __restrict__ dst,
                             int* __restrict__ counts, int E, int N) {
    int e = blockIdx.x * blockDim.x + threadIdx.x;
    if (e < E) {
        int d = dst[e];
        if (d >= 0 && d < N) atomicAdd(&counts[d], 1);
    }
}

__global__ void dinv_kernel(const int* __restrict__ counts,
                            float* __restrict__ dinv, int n) {
    int i = blockIdx.x * blockDim.x + threadIdx.x;
    if (i < n) {
        // deg includes the added self-loop -> always >= 1
        float deg = (float)(counts[i] + 1);
        dinv[i] = 1.0f / sqrtf(deg);
    }
}

// Single-block exclusive scan over counts -> row_start[0..n], cursor copy.
__global__ void scan_kernel(const int* __restrict__ counts,
                            int* __restrict__ row_start,
                            int* __restrict__ cursor, int n) {
    __shared__ int sdata[1024];
    __shared__ int s_base;
    int tid = threadIdx.x;
    if (tid == 0) s_base = 0;
    __syncthreads();
    for (int start = 0; start < n; start += 1024) {
        int i = start + tid;
        int v = (i < n) ? counts[i] : 0;
        sdata[tid] = v;
        __syncthreads();
        #pragma unroll
        for (int off = 1; off < 1024; off *= 2) {
            int t2 = (tid >= off) ? sdata[tid - off] : 0;
            __syncthreads();
            sdata[tid] += t2;
            __syncthreads();
        }
        int incl = sdata[tid];
        int excl = incl - v;
        if (i < n) {
            int val = s_base + excl;
            row_start[i] = val;
            cursor[i] = val;
        }
        __syncthreads();
        if (tid == 1023) s_base += incl;  // chunk total
        __syncthreads();
    }
    if (tid == 0) row_start[n] = s_base;
}

__global__ void scatter_kernel(const int* __restrict__ src,
                               const int* __restrict__ dst,
                               int* __restrict__ cursor,
                               int* __restrict__ csr_src, int E, int N) {
    int e = blockIdx.x * blockDim.x + threadIdx.x;
    if (e < E) {
        int d = dst[e];
        if (d < 0 || d >= N) return;
        int pos = atomicAdd(&cursor[d], 1);
        if (pos >= 0 && pos < E) csr_src[pos] = src[e];
    }
}

// ---------------- Aggregation ----------------
// out[n] = dinv[n]*(sum_e dinv[s]*feat[s] + dinv[n]*feat[n])
// One wave (64 lanes) per node; float2 per lane -> 128 feats, 512B coalesced row reads.
template <bool EPILOGUE>
__global__ void agg_kernel(const float* __restrict__ feat,
                           const float* __restrict__ dinv,
                           const int* __restrict__ row_start,
                           const int* __restrict__ csr_src,
                           const float* __restrict__ bias,
                           float* __restrict__ out) {
    int n = blockIdx.x;
    int f = threadIdx.x;  // 0..63
    const float2* feat2 = (const float2*)feat;
    float dn = dinv[n];
    float2 v = feat2[(size_t)n * 64 + f];
    float accx = dn * v.x;
    float accy = dn * v.y;
    int e0 = row_start[n];
    int e1 = row_start[n + 1];
    for (int e = e0; e < e1; ++e) {
        int s = csr_src[e];           // wave-uniform -> scalar load
        float ds = dinv[s];           // wave-uniform -> scalar load
        float2 w = feat2[(size_t)s * 64 + f];
        accx = fmaf(ds, w.x, accx);
        accy = fmaf(ds, w.y, accy);
    }
    accx *= dn;
    accy *= dn;
    if (EPILOGUE) {
        accx = fmaxf(accx + bias[2 * f], 0.0f);
        accy = fmaxf(accy + bias[2 * f + 1], 0.0f);
    }
    float2 r;
    r.x = accx;
    r.y = accy;
    ((float2*)out)[(size_t)n * 64 + f] = r;
}

// ---------------- fp32 tiled GEMM: C[M,N] = A[M,K] @ B[K,N] (+bias, relu) ----------------
// 64x64 tile, 256 threads, 4x4 microtile, BK=16.
template <bool BIAS_RELU>
__global__ void gemm_kernel(const float* __restrict__ A,
                            const float* __restrict__ B,
                            const float* __restrict__ bias,
                            float* __restrict__ C, int M, int N, int K) {
    __shared__ float As[16][65];
    __shared__ float Bs[16][64];
    int tid = threadIdx.x;
    int n0 = blockIdx.x * 64;
    int m0 = blockIdx.y * 64;
    int tx = tid & 15;
    int ty = tid >> 4;
    float acc[4][4] = {};
    for (int k0 = 0; k0 < K; k0 += 16) {
        #pragma unroll
        for (int i = 0; i < 4; i++) {
            int lin = tid + 256 * i;        // 0..1023 over 64x16 A tile
            int m = lin >> 4;
            int k = lin & 15;
            float v = 0.0f;
            if (m0 + m < M) v = A[(size_t)(m0 + m) * K + k0 + k];
            As[k][m] = v;
        }
        #pragma unroll
        for (int i = 0; i < 4; i++) {
            int lin = tid + 256 * i;        // 0..1023 over 16x64 B tile
            int k = lin >> 6;
            int n = lin & 63;
            Bs[k][n] = B[(size_t)(k0 + k) * N + n0 + n];
        }
        __syncthreads();
        #pragma unroll
        for (int k = 0; k < 16; k++) {
            float ra[4], rb[4];
            #pragma unroll
            for (int i = 0; i < 4; i++) ra[i] = As[k][ty * 4 + i];
            #pragma unroll
            for (int j = 0; j < 4; j++) rb[j] = Bs[k][tx * 4 + j];
            #pragma unroll
            for (int i = 0; i < 4; i++)
                #pragma unroll
                for (int j = 0; j < 4; j++)
                    acc[i][j] = fmaf(ra[i], rb[j], acc[i][j]);
        }
        __syncthreads();
    }
    #pragma unroll
    for (int i = 0; i < 4; i++) {
        int m = m0 + ty * 4 + i;
        if (m >= M) continue;
        #pragma unroll
        for (int j = 0; j < 4; j++) {
            int n = n0 + tx * 4 + j;
            float v = acc[i][j];
            if (BIAS_RELU) v = fmaxf(v + bias[n], 0.0f);
            C[(size_t)m * N + n] = v;
        }
    }
}

// ---------------- launch ----------------

static inline size_t align512(size_t x) { return (x + 511) & ~(size_t)511; }

extern "C" void kernel_launch(void* const* d_in, const int* in_sizes, int n_in,
                              void* d_out, int out_size, void* d_ws, size_t ws_size,
                              hipStream_t stream) {
    const float* x = (const float*)d_in[0];
    const int* ei = (const int*)d_in[1];     // harness passes integer inputs as int32
    const float* W1 = (const float*)d_in[2];
    const float* b1 = (const float*)d_in[3];
    const float* W2 = (const float*)d_in[4];
    const float* b2 = (const float*)d_in[5];
    float* out = (float*)d_out;

    const int N = in_sizes[0] / N_FEAT;      // 10000
    const int E = in_sizes[1] / 2;           // 640000
    const int* src = ei;
    const int* dst = ei + E;

    // workspace carve-up (~18 MB)
    char* ws = (char*)d_ws;
    size_t off = 0;
    float* dinv = (float*)(ws + off);  off += align512((size_t)N * 4);
    int* counts = (int*)(ws + off);    off += align512((size_t)N * 4);
    int* row_start = (int*)(ws + off); off += align512((size_t)(N + 1) * 4);
    int* cursor = (int*)(ws + off);    off += align512((size_t)N * 4);
    int* csr_src = (int*)(ws + off);   off += align512((size_t)E * 4);
    float* h = (float*)(ws + off);     off += align512((size_t)N * HID * 4);
    float* t = (float*)(ws + off);     off += align512((size_t)N * OUT_CH * 4);
    (void)ws_size;
    // layer-1 aggregate reuses d_out (consumed by gemm1 before final write)
    float* agg1 = out;

    // 1. CSR build
    zero_counts_kernel<<<(N + 255) / 256, 256, 0, stream>>>(counts, N);
    count_kernel<<<(E + 255) / 256, 256, 0, stream>>>(dst, counts, E, N);
    dinv_kernel<<<(N + 255) / 256, 256, 0, stream>>>(counts, dinv, N);
    scan_kernel<<<1, 1024, 0, stream>>>(counts, row_start, cursor, N);
    scatter_kernel<<<(E + 255) / 256, 256, 0, stream>>>(src, dst, cursor, csr_src, E, N);

    // 2. Layer 1: agg1 = A_norm @ x  (aggregate-first, 128 feats)
    agg_kernel<false><<<N, 64, 0, stream>>>(x, dinv, row_start, csr_src, nullptr, agg1);

    // 3. h = relu(agg1 @ W1 + b1)   [N,128]@[128,256]
    {
        dim3 grid(HID / 64, (N + 63) / 64);
        gemm_kernel<true><<<grid, 256, 0, stream>>>(agg1, W1, b1, h, N, HID, N_FEAT);
    }

    // 4. t = h @ W2                  [N,256]@[256,128]
    {
        dim3 grid(OUT_CH / 64, (N + 63) / 64);
        gemm_kernel<false><<<grid, 256, 0, stream>>>(h, W2, nullptr, t, N, OUT_CH, HID);
    }

    // 5. out = relu(A_norm @ t + b2) (aggregate with fused bias+relu)
    agg_kernel<true><<<N, 64, 0, stream>>>(t, dinv, row_start, csr_src, b2, out);
}

// Round 3
// 277.846 us; speedup vs baseline: 1.1517x; 1.1517x over previous
//
#include <hip/hip_runtime.h>

#define N_FEAT 128
#define HID 256
#define OUT_CH 128

// ---------------- CSR build ----------------

__global__ void count_kernel(const int* __restrict__ dst,
                             int* __restrict__ counts, int E, int N) {
    int e = blockIdx.x * blockDim.x + threadIdx.x;
    if (e < E) {
        int d = dst[e];
        if (d >= 0 && d < N) atomicAdd(&counts[d], 1);
    }
}

// Single-block hybrid scan: 1024 threads, each handles `per` consecutive
// elements sequentially; wave shfl-scan + cross-wave combine (2 barriers).
// Also emits dinv[i] = rsqrt(counts[i]+1).
#define SCAN_T 1024
#define SCAN_MAX_PER 16
__global__ __launch_bounds__(SCAN_T)
void scan_dinv_kernel(const int* __restrict__ counts,
                      int* __restrict__ row_start,
                      int* __restrict__ cursor,
                      float* __restrict__ dinv, int n) {
    int tid = threadIdx.x;
    int per = (n + SCAN_T - 1) / SCAN_T;   // 10 for n=10000
    int base = tid * per;
    int local[SCAN_MAX_PER];
    int sum = 0;
    for (int j = 0; j < per; j++) {
        int i = base + j;
        int c = (i < n) ? counts[i] : 0;
        local[j] = sum;                    // thread-local exclusive prefix
        sum += c;
        if (i < n) dinv[i] = rsqrtf((float)(c + 1));
    }
    int lane = tid & 63;
    int wave = tid >> 6;                   // 0..15
    // inclusive wave scan of thread sums
    int incl = sum;
    #pragma unroll
    for (int off = 1; off < 64; off <<= 1) {
        int t = __shfl_up(incl, off, 64);
        if (lane >= off) incl += t;
    }
    __shared__ int wsum[16];
    __shared__ int woff[16];
    if (lane == 63) wsum[wave] = incl;
    __syncthreads();
    if (wave == 0) {
        int w = (lane < 16) ? wsum[lane] : 0;
        int v = w;
        #pragma unroll
        for (int off = 1; off < 16; off <<= 1) {
            int t = __shfl_up(v, off, 64);
            if (lane >= off) v += t;
        }
        if (lane < 16) woff[lane] = v - w; // exclusive wave offset
    }
    __syncthreads();
    int thread_excl = woff[wave] + (incl - sum);
    for (int j = 0; j < per; j++) {
        int i = base + j;
        if (i < n) {
            int v = thread_excl + local[j];
            row_start[i] = v;
            cursor[i] = v;
        }
    }
    if (tid == SCAN_T - 1) row_start[n] = thread_excl + sum;
}

__global__ void scatter_kernel(const int* __restrict__ src,
                               const int* __restrict__ dst,
                               int* __restrict__ cursor,
                               int* __restrict__ csr_src, int E, int N) {
    int e = blockIdx.x * blockDim.x + threadIdx.x;
    if (e < E) {
        int d = dst[e];
        if (d < 0 || d >= N) return;
        int pos = atomicAdd(&cursor[d], 1);
        if (pos >= 0 && pos < E) csr_src[pos] = src[e];
    }
}

// ---------------- feature pre-scale: xs[n,:] = dinv[n] * x[n,:] ----------------
__global__ void prescale_kernel(const float* __restrict__ x,
                                const float* __restrict__ dinv,
                                float* __restrict__ xs, int total4) {
    int i = blockIdx.x * blockDim.x + threadIdx.x;   // one float4 per thread
    if (i < total4) {
        int row = i >> 5;                            // 32 float4 per 128-f row
        float d = dinv[row];
        float4 v = ((const float4*)x)[i];
        v.x *= d; v.y *= d; v.z *= d; v.w *= d;
        ((float4*)xs)[i] = v;
    }
}

// ---------------- Aggregation ----------------
// feat is PRE-SCALED by dinv. out[n] = dn * (feat[n] + sum_e feat[src_e]),
// i.e. the full symmetric-norm GCN aggregate incl. self-loop.
// 4 waves/block, one node per wave, float2 per lane, edge loop unrolled x8.
template <bool EPILOGUE>
__global__ __launch_bounds__(256)
void agg_kernel(const float* __restrict__ feat,
                const float* __restrict__ dinv,
                const int* __restrict__ row_start,
                const int* __restrict__ csr_src,
                const float* __restrict__ bias,
                float* __restrict__ out, int N) {
    int wave = threadIdx.x >> 6;
    int n = blockIdx.x * 4 + wave;
    if (n >= N) return;
    int f = threadIdx.x & 63;
    const float2* feat2 = (const float2*)feat;
    float dn = dinv[n];
    float2 v = feat2[(size_t)n * 64 + f];   // self-loop term (pre-scaled)
    float accx = v.x;
    float accy = v.y;
    int e0 = row_start[n];
    int e1 = row_start[n + 1];
    int e = e0;
    for (; e + 8 <= e1; e += 8) {
        int s0 = csr_src[e + 0], s1 = csr_src[e + 1];
        int s2 = csr_src[e + 2], s3 = csr_src[e + 3];
        int s4 = csr_src[e + 4], s5 = csr_src[e + 5];
        int s6 = csr_src[e + 6], s7 = csr_src[e + 7];
        float2 w0 = feat2[(size_t)s0 * 64 + f];
        float2 w1 = feat2[(size_t)s1 * 64 + f];
        float2 w2 = feat2[(size_t)s2 * 64 + f];
        float2 w3 = feat2[(size_t)s3 * 64 + f];
        float2 w4 = feat2[(size_t)s4 * 64 + f];
        float2 w5 = feat2[(size_t)s5 * 64 + f];
        float2 w6 = feat2[(size_t)s6 * 64 + f];
        float2 w7 = feat2[(size_t)s7 * 64 + f];
        accx += w0.x + w1.x + w2.x + w3.x + w4.x + w5.x + w6.x + w7.x;
        accy += w0.y + w1.y + w2.y + w3.y + w4.y + w5.y + w6.y + w7.y;
    }
    for (; e < e1; ++e) {
        int s = csr_src[e];
        float2 w = feat2[(size_t)s * 64 + f];
        accx += w.x;
        accy += w.y;
    }
    accx *= dn;
    accy *= dn;
    if (EPILOGUE) {
        float2 b = ((const float2*)bias)[f];
        accx = fmaxf(accx + b.x, 0.0f);
        accy = fmaxf(accy + b.y, 0.0f);
    }
    float2 r;
    r.x = accx;
    r.y = accy;
    ((float2*)out)[(size_t)n * 64 + f] = r;
}

// ---------------- fp32 tiled GEMM: C[M,N] = A[M,K] @ B[K,N] ----------------
// 64x64 tile, 256 threads, 4x4 microtile, BK=16.
// BIAS_RELU: C = relu(C + bias[n]).  RSCALE: C[m,:] *= rscale[m].
template <bool BIAS_RELU, bool RSCALE>
__global__ __launch_bounds__(256)
void gemm_kernel(const float* __restrict__ A,
                 const float* __restrict__ B,
                 const float* __restrict__ bias,
                 const float* __restrict__ rscale,
                 float* __restrict__ C, int M, int N, int K) {
    __shared__ float As[16][65];
    __shared__ float Bs[16][64];
    int tid = threadIdx.x;
    int n0 = blockIdx.x * 64;
    int m0 = blockIdx.y * 64;
    int tx = tid & 15;
    int ty = tid >> 4;
    float acc[4][4] = {};
    for (int k0 = 0; k0 < K; k0 += 16) {
        #pragma unroll
        for (int i = 0; i < 4; i++) {
            int lin = tid + 256 * i;
            int m = lin >> 4;
            int k = lin & 15;
            float v = 0.0f;
            if (m0 + m < M) v = A[(size_t)(m0 + m) * K + k0 + k];
            As[k][m] = v;
        }
        #pragma unroll
        for (int i = 0; i < 4; i++) {
            int lin = tid + 256 * i;
            int k = lin >> 6;
            int n = lin & 63;
            Bs[k][n] = B[(size_t)(k0 + k) * N + n0 + n];
        }
        __syncthreads();
        #pragma unroll
        for (int k = 0; k < 16; k++) {
            float ra[4], rb[4];
            #pragma unroll
            for (int i = 0; i < 4; i++) ra[i] = As[k][ty * 4 + i];
            #pragma unroll
            for (int j = 0; j < 4; j++) rb[j] = Bs[k][tx * 4 + j];
            #pragma unroll
            for (int i = 0; i < 4; i++)
                #pragma unroll
                for (int j = 0; j < 4; j++)
                    acc[i][j] = fmaf(ra[i], rb[j], acc[i][j]);
        }
        __syncthreads();
    }
    #pragma unroll
    for (int i = 0; i < 4; i++) {
        int m = m0 + ty * 4 + i;
        if (m >= M) continue;
        float rs = RSCALE ? rscale[m] : 1.0f;
        #pragma unroll
        for (int j = 0; j < 4; j++) {
            int n = n0 + tx * 4 + j;
            float v = acc[i][j];
            if (RSCALE) v *= rs;
            if (BIAS_RELU) v = fmaxf(v + bias[n], 0.0f);
            C[(size_t)m * N + n] = v;
        }
    }
}

// ---------------- launch ----------------

static inline size_t align512(size_t x) { return (x + 511) & ~(size_t)511; }

extern "C" void kernel_launch(void* const* d_in, const int* in_sizes, int n_in,
                              void* d_out, int out_size, void* d_ws, size_t ws_size,
                              hipStream_t stream) {
    const float* x = (const float*)d_in[0];
    const int* ei = (const int*)d_in[1];     // int inputs arrive as int32
    const float* W1 = (const float*)d_in[2];
    const float* b1 = (const float*)d_in[3];
    const float* W2 = (const float*)d_in[4];
    const float* b2 = (const float*)d_in[5];
    float* out = (float*)d_out;

    const int N = in_sizes[0] / N_FEAT;      // 10000
    const int E = in_sizes[1] / 2;           // 640000
    const int* src = ei;
    const int* dst = ei + E;

    // workspace carve-up
    char* ws = (char*)d_ws;
    size_t off = 0;
    float* dinv = (float*)(ws + off);  off += align512((size_t)N * 4);
    int* counts = (int*)(ws + off);    off += align512((size_t)N * 4);
    int* row_start = (int*)(ws + off); off += align512((size_t)(N + 1) * 4);
    int* cursor = (int*)(ws + off);    off += align512((size_t)N * 4);
    int* csr_src = (int*)(ws + off);   off += align512((size_t)E * 4);
    float* xs = (float*)(ws + off);    off += align512((size_t)N * N_FEAT * 4);
    float* h = (float*)(ws + off);     off += align512((size_t)N * HID * 4);
    float* t = (float*)(ws + off);     off += align512((size_t)N * OUT_CH * 4);
    (void)ws_size;
    float* agg1 = out;   // layer-1 aggregate borrows d_out (consumed by gemm1)

    // 1. CSR build + dinv
    hipMemsetAsync(counts, 0, (size_t)N * 4, stream);
    count_kernel<<<(E + 255) / 256, 256, 0, stream>>>(dst, counts, E, N);
    scan_dinv_kernel<<<1, SCAN_T, 0, stream>>>(counts, row_start, cursor, dinv, N);
    scatter_kernel<<<(E + 255) / 256, 256, 0, stream>>>(src, dst, cursor, csr_src, E, N);

    // 2. xs = dinv[row] * x  (pre-scaled features for layer-1 aggregation)
    {
        int total4 = N * N_FEAT / 4;
        prescale_kernel<<<(total4 + 255) / 256, 256, 0, stream>>>(x, dinv, xs, total4);
    }

    // 3. agg1 = A_norm @ x
    agg_kernel<false><<<(N + 3) / 4, 256, 0, stream>>>(xs, dinv, row_start, csr_src,
                                                       nullptr, agg1, N);

    // 4. h = relu(agg1 @ W1 + b1)   [N,128]@[128,256]
    {
        dim3 grid(HID / 64, (N + 63) / 64);
        gemm_kernel<true, false><<<grid, 256, 0, stream>>>(agg1, W1, b1, nullptr,
                                                           h, N, HID, N_FEAT);
    }

    // 5. t = dinv[m] * (h @ W2)     [N,256]@[256,128], pre-scaled for agg2
    {
        dim3 grid(OUT_CH / 64, (N + 63) / 64);
        gemm_kernel<false, true><<<grid, 256, 0, stream>>>(h, W2, nullptr, dinv,
                                                           t, N, OUT_CH, HID);
    }

    // 6. out = relu(A_norm-aggregate of t + b2)
    agg_kernel<true><<<(N + 3) / 4, 256, 0, stream>>>(t, dinv, row_start, csr_src,
                                                      b2, out, N);
}

// Round 4
// 239.762 us; speedup vs baseline: 1.3347x; 1.1588x over previous
//
#include <hip/hip_runtime.h>

#define N_FEAT 128
#define HID 256
#define OUT_CH 128

#define NB 256        // CSR-build blocks (per-block histograms)
#define MAXN 10240    // LDS histogram capacity (N=10000)

// ---------------- CSR build: LDS-histogram counting sort ----------------

// Per-block histogram of dst over this block's edge chunk.
__global__ __launch_bounds__(256)
void hist_kernel(const int* __restrict__ dst, int* __restrict__ bh,
                 int E, int N, int chunk) {
    __shared__ int hist[MAXN];
    for (int i = threadIdx.x; i < N; i += 256) hist[i] = 0;
    __syncthreads();
    int base = blockIdx.x * chunk;
    int lim = min(chunk, E - base);
    for (int i = threadIdx.x; i < lim; i += 256) {
        int d = dst[base + i];
        if (d >= 0 && d < N) atomicAdd(&hist[d], 1);
    }
    __syncthreads();
    int* out = bh + (size_t)blockIdx.x * N;
    for (int i = threadIdx.x; i < N; i += 256) out[i] = hist[i];
}

// counts[j] = sum_b bh[b][j]
__global__ __launch_bounds__(256)
void reduce_kernel(const int* __restrict__ bh, int* __restrict__ counts, int N) {
    int j = blockIdx.x * 256 + threadIdx.x;
    if (j >= N) return;
    int s = 0;
    for (int b = 0; b < NB; b++) s += bh[(size_t)b * N + j];
    counts[j] = s;
}

// Single-block hybrid scan: row_start = exclusive-scan(counts), dinv = rsqrt(deg+1).
#define SCAN_T 1024
#define SCAN_MAX_PER 16
__global__ __launch_bounds__(SCAN_T)
void scan_dinv_kernel(const int* __restrict__ counts,
                      int* __restrict__ row_start,
                      float* __restrict__ dinv, int n) {
    int tid = threadIdx.x;
    int per = (n + SCAN_T - 1) / SCAN_T;   // 10 for n=10000
    int base = tid * per;
    int local[SCAN_MAX_PER];
    int sum = 0;
    for (int j = 0; j < per; j++) {
        int i = base + j;
        int c = (i < n) ? counts[i] : 0;
        local[j] = sum;
        sum += c;
        if (i < n) dinv[i] = rsqrtf((float)(c + 1));
    }
    int lane = tid & 63;
    int wave = tid >> 6;
    int incl = sum;
    #pragma unroll
    for (int off = 1; off < 64; off <<= 1) {
        int t = __shfl_up(incl, off, 64);
        if (lane >= off) incl += t;
    }
    __shared__ int wsum[16];
    __shared__ int woff[16];
    if (lane == 63) wsum[wave] = incl;
    __syncthreads();
    if (wave == 0) {
        int w = (lane < 16) ? wsum[lane] : 0;
        int v = w;
        #pragma unroll
        for (int off = 1; off < 16; off <<= 1) {
            int t = __shfl_up(v, off, 64);
            if (lane >= off) v += t;
        }
        if (lane < 16) woff[lane] = v - w;
    }
    __syncthreads();
    int thread_excl = woff[wave] + (incl - sum);
    for (int j = 0; j < per; j++) {
        int i = base + j;
        if (i < n) row_start[i] = thread_excl + local[j];
    }
    if (tid == SCAN_T - 1) row_start[n] = thread_excl + sum;
}

// bh[b][j] <- row_start[j] + sum_{b'<b} bh[b'][j]   (per-block scatter bases)
__global__ __launch_bounds__(256)
void base_kernel(int* __restrict__ bh, const int* __restrict__ row_start, int N) {
    int j = blockIdx.x * 256 + threadIdx.x;
    if (j >= N) return;
    int run = row_start[j];
    for (int b = 0; b < NB; b++) {
        size_t idx = (size_t)b * N + j;
        int t = bh[idx];
        bh[idx] = run;
        run += t;
    }
}

// Scatter via LDS cursors (no global atomics).
__global__ __launch_bounds__(256)
void scat_kernel(const int* __restrict__ src, const int* __restrict__ dst,
                 const int* __restrict__ bh, int* __restrict__ csr_src,
                 int E, int N, int chunk) {
    __shared__ int cur[MAXN];
    const int* basep = bh + (size_t)blockIdx.x * N;
    for (int i = threadIdx.x; i < N; i += 256) cur[i] = basep[i];
    __syncthreads();
    int base = blockIdx.x * chunk;
    int lim = min(chunk, E - base);
    for (int i = threadIdx.x; i < lim; i += 256) {
        int e = base + i;
        int d = dst[e];
        if (d < 0 || d >= N) continue;
        int pos = atomicAdd(&cur[d], 1);
        if ((unsigned)pos < (unsigned)E) csr_src[pos] = src[e];
    }
}

// ---------------- feature pre-scale: xs[n,:] = dinv[n] * x[n,:] ----------------
__global__ void prescale_kernel(const float* __restrict__ x,
                                const float* __restrict__ dinv,
                                float* __restrict__ xs, int total4) {
    int i = blockIdx.x * blockDim.x + threadIdx.x;
    if (i < total4) {
        int row = i >> 5;                // 32 float4 per 128-f row
        float d = dinv[row];
        float4 v = ((const float4*)x)[i];
        v.x *= d; v.y *= d; v.z *= d; v.w *= d;
        ((float4*)xs)[i] = v;
    }
}

// ---------------- Aggregation ----------------
// feat PRE-SCALED by dinv. out[n] = dn * (feat[n] + sum_e feat[src_e]).
// 4 waves/block, one node per wave, float2/lane, edge loop unrolled x16.
template <bool EPILOGUE>
__global__ __launch_bounds__(256)
void agg_kernel(const float* __restrict__ feat,
                const float* __restrict__ dinv,
                const int* __restrict__ row_start,
                const int* __restrict__ csr_src,
                const float* __restrict__ bias,
                float* __restrict__ out, int N) {
    int wave = threadIdx.x >> 6;
    int n = blockIdx.x * 4 + wave;
    if (n >= N) return;
    int f = threadIdx.x & 63;
    const float2* feat2 = (const float2*)feat;
    float dn = dinv[n];
    float2 v = feat2[(size_t)n * 64 + f];
    float accx = v.x;
    float accy = v.y;
    int e0 = row_start[n];
    int e1 = row_start[n + 1];
    int e = e0;
    for (; e + 16 <= e1; e += 16) {
        int s[16];
        #pragma unroll
        for (int j = 0; j < 16; j++) s[j] = csr_src[e + j];
        float2 w[16];
        #pragma unroll
        for (int j = 0; j < 16; j++) w[j] = feat2[(size_t)s[j] * 64 + f];
        #pragma unroll
        for (int j = 0; j < 16; j++) { accx += w[j].x; accy += w[j].y; }
    }
    for (; e + 4 <= e1; e += 4) {
        int s0 = csr_src[e], s1 = csr_src[e + 1];
        int s2 = csr_src[e + 2], s3 = csr_src[e + 3];
        float2 w0 = feat2[(size_t)s0 * 64 + f];
        float2 w1 = feat2[(size_t)s1 * 64 + f];
        float2 w2 = feat2[(size_t)s2 * 64 + f];
        float2 w3 = feat2[(size_t)s3 * 64 + f];
        accx += w0.x + w1.x + w2.x + w3.x;
        accy += w0.y + w1.y + w2.y + w3.y;
    }
    for (; e < e1; ++e) {
        int s = csr_src[e];
        float2 w = feat2[(size_t)s * 64 + f];
        accx += w.x;
        accy += w.y;
    }
    accx *= dn;
    accy *= dn;
    if (EPILOGUE) {
        float2 b = ((const float2*)bias)[f];
        accx = fmaxf(accx + b.x, 0.0f);
        accy = fmaxf(accy + b.y, 0.0f);
    }
    float2 r;
    r.x = accx;
    r.y = accy;
    ((float2*)out)[(size_t)n * 64 + f] = r;
}

// ---------------- fp32 tiled GEMM: C[M,N] = A[M,K] @ B[K,N] ----------------
template <bool BIAS_RELU, bool RSCALE>
__global__ __launch_bounds__(256)
void gemm_kernel(const float* __restrict__ A,
                 const float* __restrict__ B,
                 const float* __restrict__ bias,
                 const float* __restrict__ rscale,
                 float* __restrict__ C, int M, int N, int K) {
    __shared__ float As[16][65];
    __shared__ float Bs[16][64];
    int tid = threadIdx.x;
    int n0 = blockIdx.x * 64;
    int m0 = blockIdx.y * 64;
    int tx = tid & 15;
    int ty = tid >> 4;
    float acc[4][4] = {};
    for (int k0 = 0; k0 < K; k0 += 16) {
        #pragma unroll
        for (int i = 0; i < 4; i++) {
            int lin = tid + 256 * i;
            int m = lin >> 4;
            int k = lin & 15;
            float v = 0.0f;
            if (m0 + m < M) v = A[(size_t)(m0 + m) * K + k0 + k];
            As[k][m] = v;
        }
        #pragma unroll
        for (int i = 0; i < 4; i++) {
            int lin = tid + 256 * i;
            int k = lin >> 6;
            int n = lin & 63;
            Bs[k][n] = B[(size_t)(k0 + k) * N + n0 + n];
        }
        __syncthreads();
        #pragma unroll
        for (int k = 0; k < 16; k++) {
            float ra[4], rb[4];
            #pragma unroll
            for (int i = 0; i < 4; i++) ra[i] = As[k][ty * 4 + i];
            #pragma unroll
            for (int j = 0; j < 4; j++) rb[j] = Bs[k][tx * 4 + j];
            #pragma unroll
            for (int i = 0; i < 4; i++)
                #pragma unroll
                for (int j = 0; j < 4; j++)
                    acc[i][j] = fmaf(ra[i], rb[j], acc[i][j]);
        }
        __syncthreads();
    }
    #pragma unroll
    for (int i = 0; i < 4; i++) {
        int m = m0 + ty * 4 + i;
        if (m >= M) continue;
        float rs = RSCALE ? rscale[m] : 1.0f;
        #pragma unroll
        for (int j = 0; j < 4; j++) {
            int n = n0 + tx * 4 + j;
            float v = acc[i][j];
            if (RSCALE) v *= rs;
            if (BIAS_RELU) v = fmaxf(v + bias[n], 0.0f);
            C[(size_t)m * N + n] = v;
        }
    }
}

// ---------------- launch ----------------

static inline size_t align512(size_t x) { return (x + 511) & ~(size_t)511; }

extern "C" void kernel_launch(void* const* d_in, const int* in_sizes, int n_in,
                              void* d_out, int out_size, void* d_ws, size_t ws_size,
                              hipStream_t stream) {
    const float* x = (const float*)d_in[0];
    const int* ei = (const int*)d_in[1];
    const float* W1 = (const float*)d_in[2];
    const float* b1 = (const float*)d_in[3];
    const float* W2 = (const float*)d_in[4];
    const float* b2 = (const float*)d_in[5];
    float* out = (float*)d_out;

    const int N = in_sizes[0] / N_FEAT;      // 10000
    const int E = in_sizes[1] / 2;           // 640000
    const int* src = ei;
    const int* dst = ei + E;

    // workspace carve-up
    char* ws = (char*)d_ws;
    size_t off = 0;
    float* dinv = (float*)(ws + off);  off += align512((size_t)N * 4);
    int* counts = (int*)(ws + off);    off += align512((size_t)N * 4);
    int* row_start = (int*)(ws + off); off += align512((size_t)(N + 1) * 4);
    int* csr_src = (int*)(ws + off);   off += align512((size_t)E * 4);
    float* xs = (float*)(ws + off);    off += align512((size_t)N * N_FEAT * 4);
    float* h = (float*)(ws + off);     off += align512((size_t)N * HID * 4);
    float* t = (float*)(ws + off);     off += align512((size_t)N * OUT_CH * 4);
    (void)ws_size;
    float* agg1 = out;         // layer-1 aggregate borrows d_out
    int* bh = (int*)h;         // per-block histograms/bases alias h
                               // (bh: NB*N*4 = 10.24MB == N*HID*4; bh dead
                               //  before gemm1 writes h)
    const int chunk = (E + NB - 1) / NB;

    // 1. CSR build (no global atomics)
    hist_kernel<<<NB, 256, 0, stream>>>(dst, bh, E, N, chunk);
    reduce_kernel<<<(N + 255) / 256, 256, 0, stream>>>(bh, counts, N);
    scan_dinv_kernel<<<1, SCAN_T, 0, stream>>>(counts, row_start, dinv, N);
    base_kernel<<<(N + 255) / 256, 256, 0, stream>>>(bh, row_start, N);
    scat_kernel<<<NB, 256, 0, stream>>>(src, dst, bh, csr_src, E, N, chunk);

    // 2. xs = dinv[row] * x
    {
        int total4 = N * N_FEAT / 4;
        prescale_kernel<<<(total4 + 255) / 256, 256, 0, stream>>>(x, dinv, xs, total4);
    }

    // 3. agg1 = A_norm @ x
    agg_kernel<false><<<(N + 3) / 4, 256, 0, stream>>>(xs, dinv, row_start, csr_src,
                                                       nullptr, agg1, N);

    // 4. h = relu(agg1 @ W1 + b1)
    {
        dim3 grid(HID / 64, (N + 63) / 64);
        gemm_kernel<true, false><<<grid, 256, 0, stream>>>(agg1, W1, b1, nullptr,
                                                           h, N, HID, N_FEAT);
    }

    // 5. t = dinv[m] * (h @ W2)
    {
        dim3 grid(OUT_CH / 64, (N + 63) / 64);
        gemm_kernel<false, true><<<grid, 256, 0, stream>>>(h, W2, nullptr, dinv,
                                                           t, N, OUT_CH, HID);
    }

    // 6. out = relu(A_norm-aggregate of t + b2)
    agg_kernel<true><<<(N + 3) / 4, 256, 0, stream>>>(t, dinv, row_start, csr_src,
                                                      b2, out, N);
}